// Round 7
// baseline (725.075 us; speedup 1.0000x reference)
//
#include <hip/hip_runtime.h>
#include <math.h>

// Problem constants (fixed by the reference)
#define BN_TOTAL (32 * 4096)   // B*N = 131072 queries
#define DIM 128
#define KPROTO 512
#define EPS 1e-12f
#define MARGIN 1e-4f           // fp32 top-2 gap below this -> fp64 refine
#define REF_CAP 65536          // refine-list capacity (expect ~1-3k)

// ---- workspace layout (d_ws) ----------------------------------------------
#define WS_PN_OFF    64
#define WS_IPN_OFF   (WS_PN_OFF + KPROTO * DIM * 4)
#define WS_RL_OFF    (WS_IPN_OFF + KPROTO * 8)

// ---------------------------------------------------------------------------
// Kernel A: normalize prototypes (fp64 norm), store fp64 inv-norms, zero cnt.
// ---------------------------------------------------------------------------
__global__ __launch_bounds__(64) void proto_norm_kernel(
    const float* __restrict__ protos,   // [512][128]
    float* __restrict__ pn,             // [512][128] normalized fp32
    double* __restrict__ ipn,           // [512] fp64 inverse norms
    int* __restrict__ cnt)
{
    const int k    = blockIdx.x;
    const int lane = threadIdx.x;

    if (k == 0 && lane == 0) *cnt = 0;   // zero refine counter every call

    const float a = protos[k * DIM + lane];
    const float b = protos[k * DIM + lane + 64];
    double s = (double)a * a + (double)b * b;

    #pragma unroll
    for (int off = 32; off >= 1; off >>= 1)
        s += __shfl_xor(s, off, 64);

    const double inv = 1.0 / fmax(sqrt(s), (double)EPS);
    if (lane == 0) ipn[k] = inv;

    pn[k * DIM + lane]      = (float)((double)a * inv);
    pn[k * DIM + lane + 64] = (float)((double)b * inv);
}

// ---------------------------------------------------------------------------
// Kernel B: one thread per query; fp32 scan with top-2 tracking.
// __launch_bounds__(256,2): grid is exactly 2 waves/SIMD, so min-2-waves/EU
// raises the VGPR cap to 256 at zero occupancy cost -> x-hat can live in
// registers. R5 evidence: VGPR=76 (<128) proved the compiler rematerialized
// the query loads every k-iteration -> latency-bound at VALUBusy=21.6%.
// ---------------------------------------------------------------------------
__global__ __launch_bounds__(256, 2) void assign_kernel(
    const float* __restrict__ x,      // [131072][128]
    const float* __restrict__ pn,     // [512][128] normalized (d_ws)
    const float* __restrict__ praw,   // [512][128] original prototypes
    float* __restrict__ outC,         // [131072][128] cluster centers
    float* __restrict__ outA,         // [131072] assignments (as float)
    int* __restrict__ cnt,
    int* __restrict__ rlist)
{
    const int q = blockIdx.x * 256 + threadIdx.x;

    const float4* xr4 = (const float4*)(x + (size_t)q * DIM);
    float4 xr[32];
    #pragma unroll
    for (int j = 0; j < 32; ++j) xr[j] = xr4[j];

    float s0 = 0.f, s1 = 0.f, s2 = 0.f, s3 = 0.f;
    #pragma unroll
    for (int j = 0; j < 32; ++j) {
        s0 = fmaf(xr[j].x, xr[j].x, s0);
        s1 = fmaf(xr[j].y, xr[j].y, s1);
        s2 = fmaf(xr[j].z, xr[j].z, s2);
        s3 = fmaf(xr[j].w, xr[j].w, s3);
    }
    const float nrm   = sqrtf((s0 + s1) + (s2 + s3));
    const float denom = fmaxf(nrm, EPS);
    #pragma unroll
    for (int j = 0; j < 32; ++j) {
        xr[j].x /= denom;
        xr[j].y /= denom;
        xr[j].z /= denom;
        xr[j].w /= denom;
    }

    // Opaque keep-alive: forbids rematerialization of x-hat from global
    // memory inside the k-loop (asm could have modified the values).
    #pragma unroll
    for (int j = 0; j < 32; ++j) {
        asm volatile("" : "+v"(xr[j].x), "+v"(xr[j].y),
                          "+v"(xr[j].z), "+v"(xr[j].w));
    }

    float best = -2.0f, best2 = -2.0f;
    int   bidx = 0;
    #pragma unroll 2
    for (int k = 0; k < KPROTO; ++k) {
        const float4* pk = (const float4*)(pn + (size_t)k * DIM);
        float a0 = 0.f, a1 = 0.f, a2 = 0.f, a3 = 0.f;
        #pragma unroll
        for (int j = 0; j < 32; ++j) {
            const float4 p = pk[j];   // wave-uniform -> s_load, SGPR operand
            a0 = fmaf(xr[j].x, p.x, a0);
            a1 = fmaf(xr[j].y, p.y, a1);
            a2 = fmaf(xr[j].z, p.z, a2);
            a3 = fmaf(xr[j].w, p.w, a3);
        }
        const float dot = (a0 + a1) + (a2 + a3);
        // strict > keeps the FIRST max index (matches jnp.argmax)
        if (dot > best) { best2 = best; best = dot; bidx = k; }
        else if (dot > best2) { best2 = dot; }
    }

    // near-tie -> flag for fp64 refinement
    if (best - best2 <= MARGIN) {
        const int slot = atomicAdd(cnt, 1);
        if (slot < REF_CAP) rlist[slot] = q;
    }

    const float4* pr = (const float4*)(praw + (size_t)bidx * DIM);
    float4*       oc = (float4*)(outC + (size_t)q * DIM);
    #pragma unroll
    for (int j = 0; j < 32; ++j) oc[j] = pr[j];
    outA[q] = (float)bidx;
}

// ---------------------------------------------------------------------------
// Kernel C: fp64-exact argmax for flagged queries. 1 wave per query,
// 8 protos per lane, wave argmax-reduce with min-index tie-break.
// ---------------------------------------------------------------------------
__global__ __launch_bounds__(64) void refine_kernel(
    const float* __restrict__ x,
    const float* __restrict__ praw,
    const double* __restrict__ ipn,
    const int* __restrict__ cnt,
    const int* __restrict__ rlist,
    float* __restrict__ outC,
    float* __restrict__ outA)
{
    __shared__ double xn[DIM];
    const int lane = threadIdx.x;
    int n = *cnt;
    if (n > REF_CAP) n = REF_CAP;

    for (int i = blockIdx.x; i < n; i += gridDim.x) {
        const int q = rlist[i];

        const double a = (double)x[(size_t)q * DIM + lane];
        const double b = (double)x[(size_t)q * DIM + lane + 64];
        double s = a * a + b * b;
        #pragma unroll
        for (int off = 32; off >= 1; off >>= 1)
            s += __shfl_xor(s, off, 64);
        const double inv = 1.0 / fmax(sqrt(s), (double)EPS);
        xn[lane]      = a * inv;
        xn[lane + 64] = b * inv;
        __syncthreads();

        double bv = -3.0;
        int    bi = 0;
        #pragma unroll
        for (int kk = 0; kk < 8; ++kk) {
            const int k = lane + kk * 64;   // ascending -> strict > keeps first
            const float* pr = praw + (size_t)k * DIM;
            double acc = 0.0;
            for (int d = 0; d < DIM; ++d)
                acc += (double)pr[d] * xn[d];
            const double sim = acc * ipn[k];
            if (sim > bv) { bv = sim; bi = k; }
        }
        #pragma unroll
        for (int off = 32; off >= 1; off >>= 1) {
            const double ov = __shfl_xor(bv, off, 64);
            const int    oi = __shfl_xor(bi, off, 64);
            if (ov > bv || (ov == bv && oi < bi)) { bv = ov; bi = oi; }
        }

        outC[(size_t)q * DIM + lane]      = praw[(size_t)bi * DIM + lane];
        outC[(size_t)q * DIM + lane + 64] = praw[(size_t)bi * DIM + lane + 64];
        if (lane == 0) outA[q] = (float)bi;
        __syncthreads();   // protect xn before next list entry
    }
}

// ---------------------------------------------------------------------------
extern "C" void kernel_launch(void* const* d_in, const int* in_sizes, int n_in,
                              void* d_out, int out_size, void* d_ws, size_t ws_size,
                              hipStream_t stream)
{
    const float* x      = (const float*)d_in[0];   // (32,4096,128) fp32
    const float* protos = (const float*)d_in[1];   // (512,128) fp32

    float* outC = (float*)d_out;
    float* outA = outC + (size_t)BN_TOTAL * DIM;

    int*    cnt   = (int*)d_ws;
    float*  pn    = (float*)((char*)d_ws + WS_PN_OFF);
    double* ipn   = (double*)((char*)d_ws + WS_IPN_OFF);
    int*    rlist = (int*)((char*)d_ws + WS_RL_OFF);

    proto_norm_kernel<<<KPROTO, 64, 0, stream>>>(protos, pn, ipn, cnt);
    assign_kernel<<<BN_TOTAL / 256, 256, 0, stream>>>(x, pn, protos, outC, outA,
                                                      cnt, rlist);
    refine_kernel<<<256, 64, 0, stream>>>(x, protos, ipn, cnt, rlist, outC, outA);
}

// Round 13
// 311.691 us; speedup vs baseline: 2.3263x; 2.3263x over previous
//
#include <hip/hip_runtime.h>
#include <math.h>

// Problem constants
#define BN_TOTAL (32 * 4096)   // 131072 queries
#define DIM 128
#define KPROTO 512
#define EPS 1e-12f
#define MARGIN 3e-4f           // bf16-split sim error <= ~3e-5; 10x safety
#define REF_CAP 32768

// ---- workspace layout (bytes, 256-aligned) --------------------------------
// cnt @0, ipn(512 f64) @256, pn_hi(512*128 bf16) @4352, pn_lo @135424,
// rlist(32768 int) @266496  -> end 397568 (< R5's proven 528K usage)
#define OFF_IPN 256
#define OFF_PH  4352
#define OFF_PL  135424
#define OFF_RL  266496

typedef short s16x8 __attribute__((ext_vector_type(8)));
typedef float f32x4 __attribute__((ext_vector_type(4)));

__device__ __forceinline__ unsigned short f2bf(float f) {   // RNE f32->bf16
    unsigned u = __builtin_bit_cast(unsigned, f);
    u += 0x7FFFu + ((u >> 16) & 1u);
    return (unsigned short)(u >> 16);
}
__device__ __forceinline__ float bf2f(unsigned short b) {
    return __builtin_bit_cast(float, ((unsigned)b) << 16);
}

// ---------------------------------------------------------------------------
// Kernel A: normalize prototypes (fp64), emit bf16 hi/lo split + fp64 1/norm.
// ---------------------------------------------------------------------------
__global__ __launch_bounds__(64) void proto_norm_kernel(
    const float* __restrict__ protos,
    unsigned short* __restrict__ ph,    // [512][128] bf16 bits (hi)
    unsigned short* __restrict__ pl,    // [512][128] bf16 bits (lo)
    double* __restrict__ ipn,
    int* __restrict__ cnt)
{
    const int k    = blockIdx.x;
    const int lane = threadIdx.x;
    if (k == 0 && lane == 0) *cnt = 0;

    const float a = protos[k * DIM + lane];
    const float b = protos[k * DIM + lane + 64];
    double s = (double)a * a + (double)b * b;
    #pragma unroll
    for (int off = 32; off >= 1; off >>= 1) s += __shfl_xor(s, off, 64);

    const double inv = 1.0 / fmax(sqrt(s), (double)EPS);
    if (lane == 0) ipn[k] = inv;

    const float na = (float)((double)a * inv);
    const float nb = (float)((double)b * inv);
    const unsigned short ha = f2bf(na), hb = f2bf(nb);
    ph[k * DIM + lane]      = ha;
    ph[k * DIM + lane + 64] = hb;
    pl[k * DIM + lane]      = f2bf(na - bf2f(ha));
    pl[k * DIM + lane + 64] = f2bf(nb - bf2f(hb));
}

// ---------------------------------------------------------------------------
// Kernel B: MFMA GEMM (bf16 hi/lo split) + fused argmax.
// Block = 128 queries, 4 waves. Per wave: 32 query rows x all 512 protos
// (4 chunks of 128). A-frags in registers; B chunks staged in 64 KB LDS
// (XOR-swizzled, 2-way-free ds_read_b128). mfma_f32_16x16x32_bf16:
// C/D: col=lane&15 (proto), row=(lane>>4)*4+reg (query)  [guide m89/m91].
// ---------------------------------------------------------------------------
__global__ __launch_bounds__(256, 2) void assign_mfma_kernel(
    const float* __restrict__ x,
    const unsigned short* __restrict__ ph,
    const unsigned short* __restrict__ pl,
    const float* __restrict__ praw,
    float* __restrict__ outC,
    float* __restrict__ outA,
    int* __restrict__ cnt,
    int* __restrict__ rlist)
{
    __shared__ uint4 ldsB[2][128 * 16];   // 64 KB; aliased for f32 x-staging
    __shared__ float invarr[128];
    __shared__ int   bidxArr[128];

    const int tid   = threadIdx.x;
    const int l     = tid & 63;
    const int w     = tid >> 6;
    const int qbase = blockIdx.x * 128;

    // ---- stage x (f32) into LDS (swizzled float4) + row sumsq -----------
    {
        float4* xs4 = (float4*)ldsB;
        const int r = tid >> 1, h = tid & 1;
        const float4* src = (const float4*)(x + (size_t)(qbase + r) * DIM) + h * 16;
        const int swz = (r & 7) << 1;
        float ss = 0.f;
        #pragma unroll
        for (int i = 0; i < 16; ++i) {
            float4 v = src[i];
            ss = fmaf(v.x, v.x, fmaf(v.y, v.y, fmaf(v.z, v.z, fmaf(v.w, v.w, ss))));
            const int c = h * 16 + i;
            xs4[r * 32 + (c ^ swz)] = v;
        }
        ss += __shfl_xor(ss, 1, 64);
        if (h == 0) invarr[r] = 1.0f / fmaxf(sqrtf(ss), EPS);
    }
    __syncthreads();

    // ---- build A fragments (normalized, bf16 hi/lo) in registers --------
    // A-frag (16x16x32): lane holds A[row=l&15][k=(l>>4)*8 + j], j=0..7
    s16x8 ah[2][4], al[2][4];
    {
        const float4* xs4 = (const float4*)ldsB;
        #pragma unroll
        for (int m = 0; m < 2; ++m) {
            const int r   = w * 32 + m * 16 + (l & 15);
            const float inv = invarr[r];
            const int swz = (l & 7) << 1;   // (r&7)<<1 == (l&7)<<1
            #pragma unroll
            for (int kk = 0; kk < 4; ++kk) {
                const int c0 = kk * 8 + ((l >> 4) << 1);
                const float4 v0 = xs4[r * 32 + ((c0    ) ^ swz)];
                const float4 v1 = xs4[r * 32 + ((c0 + 1) ^ swz)];
                const float f[8] = {v0.x*inv, v0.y*inv, v0.z*inv, v0.w*inv,
                                    v1.x*inv, v1.y*inv, v1.z*inv, v1.w*inv};
                s16x8 hi, lo;
                #pragma unroll
                for (int j = 0; j < 8; ++j) {
                    const unsigned short hb = f2bf(f[j]);
                    hi[j] = (short)hb;
                    lo[j] = (short)f2bf(f[j] - bf2f(hb));
                }
                ah[m][kk] = hi;
                al[m][kk] = lo;
            }
        }
    }

    float best[8], best2[8];
    int   bidx[8];
    #pragma unroll
    for (int s = 0; s < 8; ++s) { best[s] = -2.f; best2[s] = -2.f; bidx[s] = 0; }

    __syncthreads();   // everyone done reading xs4 before B-staging overwrites

    for (int c = 0; c < 4; ++c) {
        // ---- stage B chunk c (hi+lo) with XOR swizzle -------------------
        {
            const int r = tid >> 1, h = tid & 1;
            const uint4* gh = (const uint4*)(ph + (size_t)(c * 128 + r) * DIM) + h * 8;
            const uint4* gl = (const uint4*)(pl + (size_t)(c * 128 + r) * DIM) + h * 8;
            const int swz = r & 7;
            #pragma unroll
            for (int i = 0; i < 8; ++i) {
                const int cc = h * 8 + i;
                ldsB[0][r * 16 + (cc ^ swz)] = gh[i];
                ldsB[1][r * 16 + (cc ^ swz)] = gl[i];
            }
        }
        __syncthreads();

        f32x4 acc[2][8];
        #pragma unroll
        for (int m = 0; m < 2; ++m)
            #pragma unroll
            for (int n = 0; n < 8; ++n)
                acc[m][n] = (f32x4){0.f, 0.f, 0.f, 0.f};

        #pragma unroll
        for (int kk = 0; kk < 4; ++kk) {
            s16x8 bh[8], bl[8];
            const int c16 = kk * 4 + (l >> 4);
            const int swz = l & 7;          // row&7 == l&7 (rows = n*16 + (l&15))
            #pragma unroll
            for (int n = 0; n < 8; ++n) {
                const int row = n * 16 + (l & 15);
                bh[n] = __builtin_bit_cast(s16x8, ldsB[0][row * 16 + (c16 ^ swz)]);
                bl[n] = __builtin_bit_cast(s16x8, ldsB[1][row * 16 + (c16 ^ swz)]);
            }
            #pragma unroll
            for (int m = 0; m < 2; ++m)
                #pragma unroll
                for (int n = 0; n < 8; ++n) {
                    acc[m][n] = __builtin_amdgcn_mfma_f32_16x16x32_bf16(al[m][kk], bh[n], acc[m][n], 0, 0, 0);
                    acc[m][n] = __builtin_amdgcn_mfma_f32_16x16x32_bf16(ah[m][kk], bl[n], acc[m][n], 0, 0, 0);
                    acc[m][n] = __builtin_amdgcn_mfma_f32_16x16x32_bf16(ah[m][kk], bh[n], acc[m][n], 0, 0, 0);
                }
        }
        __syncthreads();   // all waves done reading B before next stage

        // ---- per-lane running top-2 (regs only; ascending proto index) --
        #pragma unroll
        for (int m = 0; m < 2; ++m)
            #pragma unroll
            for (int reg = 0; reg < 4; ++reg) {
                const int s = m * 4 + reg;
                #pragma unroll
                for (int n = 0; n < 8; ++n) {
                    const float v = acc[m][n][reg];
                    const int   p = c * 128 + n * 16 + (l & 15);
                    if (v > best[s])       { best2[s] = best[s]; best[s] = v; bidx[s] = p; }
                    else if (v > best2[s]) { best2[s] = v; }
                }
            }
    }

    // ---- cross-lane (16-lane group) top-2 argmax reduce ------------------
    #pragma unroll
    for (int s = 0; s < 8; ++s) {
        float b = best[s], b2 = best2[s];
        int   bi = bidx[s];
        #pragma unroll
        for (int o = 1; o <= 8; o <<= 1) {
            const float ob  = __shfl_xor(b,  o, 64);
            const float ob2 = __shfl_xor(b2, o, 64);
            const int   oi  = __shfl_xor(bi, o, 64);
            const float mn  = fminf(b, ob);
            b2 = fmaxf(fmaxf(b2, ob2), mn);
            if (ob > b || (ob == b && oi < bi)) { b = ob; bi = oi; }
        }
        const int m = s >> 2, reg = s & 3;
        const int rlocal = w * 32 + m * 16 + ((l >> 4) << 2) + reg;
        if ((l & 15) == 0) {
            bidxArr[rlocal] = bi;
            outA[qbase + rlocal] = (float)bi;
            if (b - b2 <= MARGIN) {
                const int slot = atomicAdd(cnt, 1);
                if (slot < REF_CAP) rlist[slot] = qbase + rlocal;
            }
        }
    }
    __syncthreads();

    // ---- centers gather --------------------------------------------------
    {
        const int r = tid >> 1, h = tid & 1;
        const int bi = bidxArr[r];
        const float4* src = (const float4*)(praw + (size_t)bi * DIM) + h * 16;
        float4*       dst = (float4*)(outC + (size_t)(qbase + r) * DIM) + h * 16;
        #pragma unroll
        for (int i = 0; i < 16; ++i) dst[i] = src[i];
    }
}

// ---------------------------------------------------------------------------
// Kernel C: fp64-exact argmax for flagged queries (unchanged from R5 pass).
// ---------------------------------------------------------------------------
__global__ __launch_bounds__(64) void refine_kernel(
    const float* __restrict__ x,
    const float* __restrict__ praw,
    const double* __restrict__ ipn,
    const int* __restrict__ cnt,
    const int* __restrict__ rlist,
    float* __restrict__ outC,
    float* __restrict__ outA)
{
    __shared__ double xn[DIM];
    const int lane = threadIdx.x;
    int n = *cnt;
    if (n > REF_CAP) n = REF_CAP;

    for (int i = blockIdx.x; i < n; i += gridDim.x) {
        const int q = rlist[i];
        const double a = (double)x[(size_t)q * DIM + lane];
        const double b = (double)x[(size_t)q * DIM + lane + 64];
        double s = a * a + b * b;
        #pragma unroll
        for (int off = 32; off >= 1; off >>= 1) s += __shfl_xor(s, off, 64);
        const double inv = 1.0 / fmax(sqrt(s), (double)EPS);
        xn[lane]      = a * inv;
        xn[lane + 64] = b * inv;
        __syncthreads();

        double bv = -3.0;
        int    bi = 0;
        #pragma unroll
        for (int kk = 0; kk < 8; ++kk) {
            const int k = lane + kk * 64;
            const float* pr = praw + (size_t)k * DIM;
            double acc = 0.0;
            for (int d = 0; d < DIM; ++d) acc += (double)pr[d] * xn[d];
            const double sim = acc * ipn[k];
            if (sim > bv) { bv = sim; bi = k; }
        }
        #pragma unroll
        for (int off = 32; off >= 1; off >>= 1) {
            const double ov = __shfl_xor(bv, off, 64);
            const int    oi = __shfl_xor(bi, off, 64);
            if (ov > bv || (ov == bv && oi < bi)) { bv = ov; bi = oi; }
        }

        outC[(size_t)q * DIM + lane]      = praw[(size_t)bi * DIM + lane];
        outC[(size_t)q * DIM + lane + 64] = praw[(size_t)bi * DIM + lane + 64];
        if (lane == 0) outA[q] = (float)bi;
        __syncthreads();
    }
}

// ---------------------------------------------------------------------------
extern "C" void kernel_launch(void* const* d_in, const int* in_sizes, int n_in,
                              void* d_out, int out_size, void* d_ws, size_t ws_size,
                              hipStream_t stream)
{
    const float* x      = (const float*)d_in[0];
    const float* protos = (const float*)d_in[1];

    float* outC = (float*)d_out;
    float* outA = outC + (size_t)BN_TOTAL * DIM;

    int*            cnt   = (int*)d_ws;
    double*         ipn   = (double*)((char*)d_ws + OFF_IPN);
    unsigned short* ph    = (unsigned short*)((char*)d_ws + OFF_PH);
    unsigned short* pl    = (unsigned short*)((char*)d_ws + OFF_PL);
    int*            rlist = (int*)((char*)d_ws + OFF_RL);

    proto_norm_kernel<<<KPROTO, 64, 0, stream>>>(protos, ph, pl, ipn, cnt);
    assign_mfma_kernel<<<BN_TOTAL / 128, 256, 0, stream>>>(x, ph, pl, protos,
                                                           outC, outA, cnt, rlist);
    refine_kernel<<<256, 64, 0, stream>>>(x, protos, ipn, cnt, rlist, outC, outA);
}